// Round 7
// baseline (55.255 us; speedup 1.0000x reference)
//
#include <hip/hip_runtime.h>
#include <hip/hip_fp16.h>

typedef unsigned short u16;
typedef unsigned int   u32;
typedef u32   u32x2  __attribute__((ext_vector_type(2)));
typedef u32   u32x4  __attribute__((ext_vector_type(4)));
typedef short short8 __attribute__((ext_vector_type(8)));
typedef float f32x4  __attribute__((ext_vector_type(4)));
typedef _Float16 half8 __attribute__((ext_vector_type(8)));

__device__ __forceinline__ u16 f2h(float f) { return __half_as_ushort(__float2half(f)); }
__device__ __forceinline__ f32x4 mfma16(short8 a, short8 b, f32x4 c) {
  return __builtin_amdgcn_mfma_f32_16x16x32_f16(
      __builtin_bit_cast(half8, a), __builtin_bit_cast(half8, b), c, 0, 0, 0);
}
__device__ __forceinline__ __half2 h2cast(u32 u) { return __builtin_bit_cast(__half2, u); }

// ---------------- fused prep: x NCHW f32 -> NHWC f16 ; weights -> MFMA order ----------------
__global__ __launch_bounds__(256) void prep_fused(const float* __restrict__ x,
                                                  const float* __restrict__ w_dc,
                                                  const float* __restrict__ w_off,
                                                  u16* __restrict__ xh,
                                                  u16* __restrict__ Wl2,
                                                  u16* __restrict__ Wol2) {
  int bid = blockIdx.x;
  int tid = threadIdx.x;
  if (bid < 512) {
    __shared__ float tile[128][65];
    int swz = (bid & 7) * 64 + (bid >> 3);
    int b = swz >> 6, h = swz & 63;
    for (int i = 0; i < 32; ++i) {
      int c = (tid >> 6) + i * 4;
      int w = tid & 63;
      tile[c][w] = x[(((size_t)b * 128 + c) * 64 + h) * 64 + w];
    }
    __syncthreads();
    u16* dst = xh + ((size_t)(b * 64 + h) * 64) * 128;
    for (int j = 0; j < 32; ++j) {
      int c = tid & 127;
      int w = (tid >> 7) + 2 * j;
      dst[w * 128 + c] = f2h(tile[c][w]);
    }
  } else {
    int idx = (bid - 512) * 256 + tid;        // 0..331775
    if (idx < 294912) {
      // Wl2 idx = (((kk*16+mtg)*4+ks)*64+lane)*8+e : o=mtg*16+(lane&15), c=ks*32+(lane>>4)*8+e
      int e = idx & 7, lane = (idx >> 3) & 63, ks = (idx >> 9) & 3;
      int mt = (idx >> 11) & 15, kk = idx >> 15;
      int o = mt * 16 + (lane & 15), c = ks * 32 + (lane >> 4) * 8 + e;
      Wl2[idx] = f2h(w_dc[(o * 128 + c) * 9 + kk]);
    } else {
      int i2 = idx - 294912;                  // 0..36863
      int e = i2 & 7, lane = (i2 >> 3) & 63, ks = (i2 >> 9) & 3;
      int mt = (i2 >> 11) & 1, kk = i2 >> 12;
      int co = mt * 16 + (lane & 15), c = ks * 32 + (lane >> 4) * 8 + e;
      Wol2[i2] = (co < 18) ? f2h(w_off[(co * 128 + c) * 9 + kk]) : (u16)0;
    }
  }
}

// ---------------- packed 12B sampling-table entry ----------------
__device__ __forceinline__ void make_entry3(u32* __restrict__ tbl, int kk,
                                            int ho, int wo, float offy, float offx) {
  int ki = kk / 3, kj = kk - ki * 3;
  float py = offy + (float)(ho + ki - 1);
  float px = offx + (float)(wo + kj - 1);
  float fy0 = floorf(py), fx0 = floorf(px);
  int y0 = (int)fy0, x0 = (int)fx0;
  float fy = py - fy0, fx = px - fx0;
  float w11 = fy * fx, w10 = fy - w11, w01 = fx - w11, w00 = 1.f - fy - fx + w11;
  bool iy0 = (y0 >= 0) & (y0 < 64), iy1 = (y0 >= -1) & (y0 < 63);
  bool ix0 = (x0 >= 0) & (x0 < 64), ix1 = (x0 >= -1) & (x0 < 63);
  int y0c = min(max(y0, 0), 63), x0c = min(max(x0, 0), 63);
  u32 addr = (u32)((y0c * 64 + x0c) * 128);            // u16-element offset, < 2^20
  u32 dxf = (x0 >= 0 && x0 < 63) ? 1u : 0u;
  u32 dyf = (y0 >= 0 && y0 < 63) ? 1u : 0u;
  u32 wA = (u32)f2h((iy0 && ix0) ? w00 : 0.f) | ((u32)f2h((iy0 && ix1) ? w01 : 0.f) << 16);
  u32 wB = (u32)f2h((iy1 && ix0) ? w10 : 0.f) | ((u32)f2h((iy1 && ix1) ? w11 : 0.f) << 16);
  int base = (kk * 64 + wo) * 3;
  tbl[base]     = addr | (dxf << 20) | (dyf << 21);
  tbl[base + 1] = wA;
  tbl[base + 2] = wB;
}

// ---------------- fused: offset conv (slab) -> table -> gather || MFMA GEMM ----------------
// 256 threads (4 waves), wave tile = 64 COUT x 64 l (mt=4, nt=4), 3 blocks/CU.
__global__ __launch_bounds__(256, 3) void deform_fused(
    const u16* __restrict__ xh, const u16* __restrict__ Wl2,
    const u16* __restrict__ Wol2, const float* __restrict__ b_off,
    const float* __restrict__ b_dc, float* __restrict__ out) {
  union SMU {
    u16 slab[3][64][128];                                // 49152 B (phase A)
    struct { u16 cols[2][64][128]; u32 tbl[1728]; } pb;  // 32768 + 6912 (phase B)
  };
  __shared__ SMU sm;
  int bid = blockIdx.x;
  int b = bid & 7, ho = bid >> 3;          // XCD <- batch
  int tid = threadIdx.x, lane = tid & 63, wv = tid >> 6;   // wv 0..3
  int ln15 = lane & 15, kg = lane >> 4;
  const u16* xb = xh + (size_t)b * 524288;

  int tl0 = tid >> 4;                      // 0..15
  int tcl = (tid & 15) * 8;                // 8-channel chunk base
  int swzc = tcl ^ ((tl0 & 7) << 3);

  // ================= phase A: stage 3-row slab once =================
  {
    u32x4 st[12];
#pragma unroll
    for (int i = 0; i < 12; ++i) {
      int T = tid + i * 256;
      int r = T >> 10, w = (T >> 4) & 63, cb = (T & 15) * 8;
      int hr = ho + r - 1; hr = hr < 0 ? -hr : (hr > 63 ? 126 - hr : hr);
      st[i] = *(const u32x4*)(xb + (hr * 64 + w) * 128 + cb);
    }
#pragma unroll
    for (int i = 0; i < 12; ++i) {
      int T = tid + i * 256;
      int r = T >> 10, w = (T >> 4) & 63, cb = (T & 15) * 8;
      *(u32x4*)&sm.slab[r][w][cb ^ ((w & 7) << 3)] = st[i];
    }
  }
  __syncthreads();

  // ---- offset conv: 72 MFMA burst per wave, no barriers ----
  int mtA = wv & 1;
  int ntb = (wv >> 1) * 2;
  int lqa = ntb * 16 + ln15, lqb = (ntb + 1) * 16 + ln15;
  f32x4 oacc0 = {0.f, 0.f, 0.f, 0.f}, oacc1 = {0.f, 0.f, 0.f, 0.f};
  __builtin_amdgcn_s_setprio(1);
#pragma unroll
  for (int kk = 0; kk < 9; ++kk) {
    int ki = kk / 3, kj = kk - ki * 3;
    int wra = lqa + kj - 1; wra = wra < 0 ? -wra : (wra > 63 ? 126 - wra : wra);
    int wrb = lqb + kj - 1; wrb = wrb < 0 ? -wrb : (wrb > 63 ? 126 - wrb : wrb);
    const u16* wb = Wol2 + ((kk * 2 + mtA) * 4) * 512 + lane * 8;
    int sba = (wra & 7) << 3, sbb = (wrb & 7) << 3;
#pragma unroll
    for (int ks = 0; ks < 4; ++ks) {
      short8 af = *(const short8*)(wb + ks * 512);
      oacc0 = mfma16(af, *(const short8*)&sm.slab[ki][wra][(ks * 32 + kg * 8) ^ sba], oacc0);
      oacc1 = mfma16(af, *(const short8*)&sm.slab[ki][wrb][(ks * 32 + kg * 8) ^ sbb], oacc1);
    }
  }
  __builtin_amdgcn_s_setprio(0);
  __syncthreads();                         // slab reads done (tbl aliases slab)

  // ---- write sampling table ----
  if (mtA == 0) {
    int kkA = 2 * kg, kkB = 2 * kg + 1;
    make_entry3(sm.pb.tbl, kkA, ho, lqa, oacc0[0] + b_off[2 * kkA], oacc0[1] + b_off[2 * kkA + 1]);
    make_entry3(sm.pb.tbl, kkB, ho, lqa, oacc0[2] + b_off[2 * kkB], oacc0[3] + b_off[2 * kkB + 1]);
    make_entry3(sm.pb.tbl, kkA, ho, lqb, oacc1[0] + b_off[2 * kkA], oacc1[1] + b_off[2 * kkA + 1]);
    make_entry3(sm.pb.tbl, kkB, ho, lqb, oacc1[2] + b_off[2 * kkB], oacc1[3] + b_off[2 * kkB + 1]);
  } else if (kg == 0) {
    make_entry3(sm.pb.tbl, 8, ho, lqa, oacc0[0] + b_off[16], oacc0[1] + b_off[17]);
    make_entry3(sm.pb.tbl, 8, ho, lqb, oacc1[0] + b_off[16], oacc1[1] + b_off[17]);
  }
  __syncthreads();                         // tbl visible

  // ================= phase B: deformable GEMM =================
  u32x4 gv[2][4];                          // 2 tasks in flight (32 VGPR)
  u32 gwAv[2], gwBv[2];
  auto gissue2 = [&](int g, int i0) {
#pragma unroll
    for (int i = 0; i < 2; ++i) {
      int l = tl0 + (i0 + i) * 16;
      int base3 = (g * 64 + l) * 3;
      u32 e0 = sm.pb.tbl[base3];
      gwAv[i] = sm.pb.tbl[base3 + 1];
      gwBv[i] = sm.pb.tbl[base3 + 2];
      const u16* p = xb + (e0 & 0xFFFFFu) + tcl;
      u32 dxv = ((e0 >> 20) & 1) << 7;
      u32 dyv = ((e0 >> 21) & 1) << 13;
      gv[i][0] = *(const u32x4*)p;
      gv[i][1] = *(const u32x4*)(p + dxv);
      gv[i][2] = *(const u32x4*)(p + dyv);
      gv[i][3] = *(const u32x4*)(p + dyv + dxv);
    }
  };
  auto gwrite2 = [&](int dbuf, int i0) {
#pragma unroll
    for (int i = 0; i < 2; ++i) {
      int l = tl0 + (i0 + i) * 16;
      __half2 wA = h2cast(gwAv[i]), wB = h2cast(gwBv[i]);
      __half2 w00 = __half2half2(wA.x), w01 = __half2half2(wA.y);
      __half2 w10 = __half2half2(wB.x), w11 = __half2half2(wB.y);
      u32x4 pv;
#pragma unroll
      for (int wd = 0; wd < 4; ++wd) {
        __half2 r = __hmul2(h2cast(gv[i][0][wd]), w00);
        r = __hfma2(h2cast(gv[i][1][wd]), w01, r);
        r = __hfma2(h2cast(gv[i][2][wd]), w10, r);
        r = __hfma2(h2cast(gv[i][3][wd]), w11, r);
        pv[wd] = __builtin_bit_cast(u32, r);
      }
      *(u32x4*)&sm.pb.cols[dbuf][l][swzc] = pv;
    }
  };

  f32x4 acc[4][4];
#pragma unroll
  for (int m = 0; m < 4; ++m)
#pragma unroll
    for (int n = 0; n < 4; ++n) acc[m][n] = (f32x4){0.f, 0.f, 0.f, 0.f};

  // prologue: gather tile 0
  gissue2(0, 0); gwrite2(0, 0);
  gissue2(0, 2); gwrite2(0, 2);
  __syncthreads();

  int swzb = (ln15 & 7) << 3;
  for (int kk = 0; kk < 9; ++kk) {
    int buf = kk & 1;
    bool more = kk < 8;
    const u16* wbase = Wl2 + (size_t)((kk * 16 + wv * 4) * 4) * 512 + lane * 8;
    // ---- half 0: A(ks 0,1) first, then gathers T01, MFMA, write ----
    short8 a0[4][2];
#pragma unroll
    for (int mt = 0; mt < 4; ++mt)
#pragma unroll
      for (int k2 = 0; k2 < 2; ++k2)
        a0[mt][k2] = *(const short8*)(wbase + (mt * 4 + k2) * 512);
    if (more) gissue2(kk + 1, 0);
    __builtin_amdgcn_s_setprio(1);
#pragma unroll
    for (int k2 = 0; k2 < 2; ++k2) {
#pragma unroll
      for (int nt = 0; nt < 4; ++nt) {
        short8 bf = *(const short8*)&sm.pb.cols[buf][nt * 16 + ln15][(k2 * 32 + kg * 8) ^ swzb];
#pragma unroll
        for (int mt = 0; mt < 4; ++mt)
          acc[mt][nt] = mfma16(a0[mt][k2], bf, acc[mt][nt]);
      }
    }
    __builtin_amdgcn_s_setprio(0);
    if (more) gwrite2(buf ^ 1, 0);
    // ---- half 1: A(ks 2,3), gathers T23, MFMA, write ----
    short8 a1[4][2];
#pragma unroll
    for (int mt = 0; mt < 4; ++mt)
#pragma unroll
      for (int k2 = 0; k2 < 2; ++k2)
        a1[mt][k2] = *(const short8*)(wbase + (mt * 4 + 2 + k2) * 512);
    if (more) gissue2(kk + 1, 2);
    __builtin_amdgcn_s_setprio(1);
#pragma unroll
    for (int k2 = 0; k2 < 2; ++k2) {
#pragma unroll
      for (int nt = 0; nt < 4; ++nt) {
        short8 bf = *(const short8*)&sm.pb.cols[buf][nt * 16 + ln15][((k2 + 2) * 32 + kg * 8) ^ swzb];
#pragma unroll
        for (int mt = 0; mt < 4; ++mt)
          acc[mt][nt] = mfma16(a1[mt][k2], bf, acc[mt][nt]);
      }
    }
    __builtin_amdgcn_s_setprio(0);
    if (more) gwrite2(buf ^ 1, 2);
    __syncthreads();
  }

  // epilogue: wave wv owns COUT [wv*64, wv*64+64)
#pragma unroll
  for (int mt = 0; mt < 4; ++mt) {
#pragma unroll
    for (int r = 0; r < 4; ++r) {
      int o = wv * 64 + mt * 16 + kg * 4 + r;
      float bias = b_dc[o];
      size_t base = ((size_t)(b * 256 + o)) * 4096 + ho * 64;
#pragma unroll
      for (int nt = 0; nt < 4; ++nt) {
        out[base + nt * 16 + ln15] = acc[mt][nt][r] + bias;
      }
    }
  }
}

extern "C" void kernel_launch(void* const* d_in, const int* in_sizes, int n_in,
                              void* d_out, int out_size, void* d_ws, size_t ws_size,
                              hipStream_t stream) {
  const float* x     = (const float*)d_in[0];
  const float* w_off = (const float*)d_in[1];
  const float* b_off = (const float*)d_in[2];
  const float* w_dc  = (const float*)d_in[3];
  const float* b_dc  = (const float*)d_in[4];
  float* out = (float*)d_out;
  char* ws = (char*)d_ws;
  u16* xh   = (u16*)ws;                                   // 8,388,608 B
  u16* Wl2  = (u16*)(ws + 8388608);                       //   589,824 B
  u16* Wol2 = (u16*)(ws + 8388608 + 589824);              //    73,728 B (tot 9.05 MB)
  prep_fused  <<<dim3(1808), dim3(256), 0, stream>>>(x, w_dc, w_off, xh, Wl2, Wol2);
  deform_fused<<<dim3(512),  dim3(256), 0, stream>>>(xh, Wl2, Wol2, b_off, b_dc, out);
}

// Round 8
// 53.650 us; speedup vs baseline: 1.0299x; 1.0299x over previous
//
#include <hip/hip_runtime.h>
#include <hip/hip_fp16.h>

typedef unsigned short u16;
typedef unsigned int   u32;
typedef u32   u32x2  __attribute__((ext_vector_type(2)));
typedef u32   u32x4  __attribute__((ext_vector_type(4)));
typedef short short8 __attribute__((ext_vector_type(8)));
typedef float f32x4  __attribute__((ext_vector_type(4)));
typedef _Float16 half8 __attribute__((ext_vector_type(8)));

__device__ __forceinline__ u16 f2h(float f) { return __half_as_ushort(__float2half(f)); }
__device__ __forceinline__ f32x4 mfma16(short8 a, short8 b, f32x4 c) {
  return __builtin_amdgcn_mfma_f32_16x16x32_f16(
      __builtin_bit_cast(half8, a), __builtin_bit_cast(half8, b), c, 0, 0, 0);
}
__device__ __forceinline__ __half2 h2cast(u32 u) { return __builtin_bit_cast(__half2, u); }
__device__ __forceinline__ int refl(int v) { return v < 0 ? -v : (v > 63 ? 126 - v : v); }

// ---------------- fused prep: x NCHW f32 -> NHWC f16 ; weights -> MFMA order ----------------
__global__ __launch_bounds__(256) void prep_fused(const float* __restrict__ x,
                                                  const float* __restrict__ w_dc,
                                                  const float* __restrict__ w_off,
                                                  u16* __restrict__ xh,
                                                  u16* __restrict__ Wl2,
                                                  u16* __restrict__ Wol2) {
  int bid = blockIdx.x;
  int tid = threadIdx.x;
  if (bid < 512) {
    __shared__ float tile[128][65];
    int swz = (bid & 7) * 64 + (bid >> 3);
    int b = swz >> 6, h = swz & 63;
    for (int i = 0; i < 32; ++i) {
      int c = (tid >> 6) + i * 4;
      int w = tid & 63;
      tile[c][w] = x[(((size_t)b * 128 + c) * 64 + h) * 64 + w];
    }
    __syncthreads();
    u16* dst = xh + ((size_t)(b * 64 + h) * 64) * 128;
    for (int j = 0; j < 32; ++j) {
      int c = tid & 127;
      int w = (tid >> 7) + 2 * j;
      dst[w * 128 + c] = f2h(tile[c][w]);
    }
  } else {
    int idx = (bid - 512) * 256 + tid;        // 0..331775
    if (idx < 294912) {
      // Wl2 idx = (((kk*16+mtile)*4+ks)*64+lane)*8+e : o=mtile*16+(lane&15), c=ks*32+(lane>>4)*8+e
      int e = idx & 7, lane = (idx >> 3) & 63, ks = (idx >> 9) & 3;
      int mt = (idx >> 11) & 15, kk = idx >> 15;
      int o = mt * 16 + (lane & 15), c = ks * 32 + (lane >> 4) * 8 + e;
      Wl2[idx] = f2h(w_dc[(o * 128 + c) * 9 + kk]);
    } else {
      int i2 = idx - 294912;                  // 0..36863
      int e = i2 & 7, lane = (i2 >> 3) & 63, ks = (i2 >> 9) & 3;
      int mt = (i2 >> 11) & 1, kk = i2 >> 12;
      int co = mt * 16 + (lane & 15), c = ks * 32 + (lane >> 4) * 8 + e;
      Wol2[i2] = (co < 18) ? f2h(w_off[(co * 128 + c) * 9 + kk]) : (u16)0;
    }
  }
}

// ---------------- sampling-table entry (LDS, per-block 32-l tile) ----------------
__device__ __forceinline__ void make_entry_lds(u32x4* __restrict__ tbl, int kk,
                                               int ho, int wo_g, int lql,
                                               float offy, float offx) {
  int ki = kk / 3, kj = kk - ki * 3;
  float py = offy + (float)(ho + ki - 1);
  float px = offx + (float)(wo_g + kj - 1);
  float fy0 = floorf(py), fx0 = floorf(px);
  int y0 = (int)fy0, x0 = (int)fx0;
  float fy = py - fy0, fx = px - fx0;
  float w11 = fy * fx, w10 = fy - w11, w01 = fx - w11, w00 = 1.f - fy - fx + w11;
  bool iy0 = (y0 >= 0) & (y0 < 64), iy1 = (y0 >= -1) & (y0 < 63);
  bool ix0 = (x0 >= 0) & (x0 < 64), ix1 = (x0 >= -1) & (x0 < 63);
  int y0c = min(max(y0, 0), 63), x0c = min(max(x0, 0), 63);
  u32 addr00 = (u32)((y0c * 64 + x0c) * 128);          // u16-element offset
  u32 dx = (x0 >= 0 && x0 < 63) ? 128u : 0u;
  u32 dy = (y0 >= 0 && y0 < 63) ? 8192u : 0u;
  u32 wA = (u32)f2h((iy0 && ix0) ? w00 : 0.f) | ((u32)f2h((iy0 && ix1) ? w01 : 0.f) << 16);
  u32 wB = (u32)f2h((iy1 && ix0) ? w10 : 0.f) | ((u32)f2h((iy1 && ix1) ? w11 : 0.f) << 16);
  u32x4 ent; ent.x = addr00; ent.y = dx | (dy << 16); ent.z = wA; ent.w = wB;
  tbl[kk * 32 + lql] = ent;
}

// ---------------- fused kernel: 32 l x 256 COUT per block, 4 waves, 4 blocks/CU ----------------
__global__ __launch_bounds__(256, 4) void deform_fused(
    const u16* __restrict__ xh, const u16* __restrict__ Wl2,
    const u16* __restrict__ Wol2, const float* __restrict__ b_off,
    const float* __restrict__ b_dc, float* __restrict__ out) {
  union SMU {
    u16 slab[3][36][128];                                // 27648 B (phase A)
    struct { u16 cols[2][32][128]; u32x4 tbl[288]; } pb; // 16384 + 4608 (phase B)
  };
  __shared__ SMU sm;
  int bid = blockIdx.x;
  int b = bid & 7, t = bid >> 3;           // batch -> XCD
  int ho = t >> 1, l0 = (t & 1) * 32;
  int tid = threadIdx.x, lane = tid & 63, wv = tid >> 6;   // wv 0..3
  int ln15 = lane & 15, kg = lane >> 4;
  const u16* xb = xh + (size_t)b * 524288;

  // ================= phase A: stage reflected 3x34(+2) slab once =================
  {
    u32x4 st[7];
#pragma unroll
    for (int i = 0; i < 7; ++i) {
      int T = tid + i * 256;               // 0..1791, valid < 1728
      if (T < 1728) {
        int r = T / 576, rem = T - r * 576;
        int j = rem >> 4, cb = (rem & 15) * 8;
        int hr = refl(ho + r - 1);
        int w = refl(l0 + j - 1);
        st[i] = *(const u32x4*)(xb + (hr * 64 + w) * 128 + cb);
      }
    }
#pragma unroll
    for (int i = 0; i < 7; ++i) {
      int T = tid + i * 256;
      if (T < 1728) {
        int r = T / 576, rem = T - r * 576;
        int j = rem >> 4, cb = (rem & 15) * 8;
        *(u32x4*)&sm.slab[r][j][cb ^ ((j & 7) << 3)] = st[i];
      }
    }
  }
  __syncthreads();

  // ---- offset conv: M=32(pad 18) x N=32 l, 36 MFMA/wave, no barriers ----
  int mtA = wv & 1, ntA = wv >> 1;
  int lql = ntA * 16 + ln15;               // local l 0..31
  f32x4 oacc = {0.f, 0.f, 0.f, 0.f};
  __builtin_amdgcn_s_setprio(1);
#pragma unroll
  for (int kk = 0; kk < 9; ++kk) {
    int ki = kk / 3, kj = kk - ki * 3;
    int j = lql + kj;                      // 0..33, reflect pre-resolved
    const u16* wb = Wol2 + ((kk * 2 + mtA) * 4) * 512 + lane * 8;
    int sbj = (j & 7) << 3;
#pragma unroll
    for (int ks = 0; ks < 4; ++ks) {
      short8 af = *(const short8*)(wb + ks * 512);
      short8 bf = *(const short8*)&sm.slab[ki][j][(ks * 32 + kg * 8) ^ sbj];
      oacc = mfma16(af, bf, oacc);
    }
  }
  __builtin_amdgcn_s_setprio(0);
  __syncthreads();                         // slab reads done (pb aliases slab)

  // ---- write sampling table ----
  if (mtA == 0) {
    int kkA = 2 * kg, kkB = 2 * kg + 1;
    make_entry_lds(sm.pb.tbl, kkA, ho, l0 + lql, lql, oacc[0] + b_off[2 * kkA], oacc[1] + b_off[2 * kkA + 1]);
    make_entry_lds(sm.pb.tbl, kkB, ho, l0 + lql, lql, oacc[2] + b_off[2 * kkB], oacc[3] + b_off[2 * kkB + 1]);
  } else if (kg == 0) {
    make_entry_lds(sm.pb.tbl, 8, ho, l0 + lql, lql, oacc[0] + b_off[16], oacc[1] + b_off[17]);
  }
  __syncthreads();                         // tbl visible

  // ================= phase B: deformable GEMM =================
  // gather task (half h): T = tid + h*256 -> l = T>>4 (0..31), chunk = (T&15)*8
  int tl0 = tid >> 4;                      // 0..15 ; +16 for h=1
  int tcl = (tid & 15) * 8;
  int swzc = tcl ^ ((tl0 & 7) << 3);       // (tl0+16)&7 == tl0&7

  u32x4 gv[4];
  u32 gwAv, gwBv;
  auto gissue = [&](int g, int h) {
    int l = tl0 + h * 16;
    u32x4 e = sm.pb.tbl[g * 32 + l];
    gwAv = e.z; gwBv = e.w;
    const u16* p = xb + e.x + tcl;
    u32 dxv = e.y & 0xffffu, dyv = e.y >> 16;
    gv[0] = *(const u32x4*)p;
    gv[1] = *(const u32x4*)(p + dxv);
    gv[2] = *(const u32x4*)(p + dyv);
    gv[3] = *(const u32x4*)(p + dyv + dxv);
  };
  auto gwrite = [&](int dbuf, int h) {
    int l = tl0 + h * 16;
    __half2 wA = h2cast(gwAv), wB = h2cast(gwBv);
    __half2 w00 = __half2half2(wA.x), w01 = __half2half2(wA.y);
    __half2 w10 = __half2half2(wB.x), w11 = __half2half2(wB.y);
    u32x4 pv;
#pragma unroll
    for (int wd = 0; wd < 4; ++wd) {
      __half2 r = __hmul2(h2cast(gv[0][wd]), w00);
      r = __hfma2(h2cast(gv[1][wd]), w01, r);
      r = __hfma2(h2cast(gv[2][wd]), w10, r);
      r = __hfma2(h2cast(gv[3][wd]), w11, r);
      pv[wd] = __builtin_bit_cast(u32, r);
    }
    *(u32x4*)&sm.pb.cols[dbuf][l][swzc] = pv;
  };

  f32x4 acc[4][2];
#pragma unroll
  for (int m = 0; m < 4; ++m) {
    acc[m][0] = (f32x4){0.f, 0.f, 0.f, 0.f};
    acc[m][1] = (f32x4){0.f, 0.f, 0.f, 0.f};
  }

  // prologue
  gissue(0, 0); gwrite(0, 0);
  gissue(0, 1); gwrite(0, 1);
  __syncthreads();

  int swzb = (ln15 & 7) << 3;
  for (int kk = 0; kk < 9; ++kk) {
    int buf = kk & 1;
    bool more = kk < 8;
    const u16* wbase = Wl2 + (size_t)kk * 32768 + lane * 8;
#pragma unroll
    for (int h = 0; h < 2; ++h) {
      // (1) A fragments for this half (ks = 2h, 2h+1), 8 x b128
      short8 a[4][2];
#pragma unroll
      for (int mt = 0; mt < 4; ++mt)
#pragma unroll
        for (int k2 = 0; k2 < 2; ++k2)
          a[mt][k2] = *(const short8*)(wbase + (size_t)(((wv * 4 + mt) * 4) + h * 2 + k2) * 512);
      // (2) next-tile gather loads for this half
      if (more) gissue(kk + 1, h);
      // (3) MFMA burst
      __builtin_amdgcn_s_setprio(1);
#pragma unroll
      for (int k2 = 0; k2 < 2; ++k2) {
        int ks = h * 2 + k2;
#pragma unroll
        for (int nt = 0; nt < 2; ++nt) {
          short8 bf = *(const short8*)&sm.pb.cols[buf][nt * 16 + ln15][(ks * 32 + kg * 8) ^ swzb];
#pragma unroll
          for (int mt = 0; mt < 4; ++mt)
            acc[mt][nt] = mfma16(a[mt][k2], bf, acc[mt][nt]);
        }
      }
      __builtin_amdgcn_s_setprio(0);
      // (4) combine + write next buffer rows for this half
      if (more) gwrite(buf ^ 1, h);
    }
    __syncthreads();
  }

  // epilogue: wave wv owns COUT [wv*64, wv*64+64), l in [l0, l0+32)
#pragma unroll
  for (int mt = 0; mt < 4; ++mt) {
#pragma unroll
    for (int r = 0; r < 4; ++r) {
      int o = wv * 64 + mt * 16 + kg * 4 + r;
      float bias = b_dc[o];
      size_t base = ((size_t)(b * 256 + o)) * 4096 + ho * 64 + l0;
      out[base + ln15]      = acc[mt][0][r] + bias;
      out[base + 16 + ln15] = acc[mt][1][r] + bias;
    }
  }
}

extern "C" void kernel_launch(void* const* d_in, const int* in_sizes, int n_in,
                              void* d_out, int out_size, void* d_ws, size_t ws_size,
                              hipStream_t stream) {
  const float* x     = (const float*)d_in[0];
  const float* w_off = (const float*)d_in[1];
  const float* b_off = (const float*)d_in[2];
  const float* w_dc  = (const float*)d_in[3];
  const float* b_dc  = (const float*)d_in[4];
  float* out = (float*)d_out;
  char* ws = (char*)d_ws;
  u16* xh   = (u16*)ws;                                   // 8,388,608 B
  u16* Wl2  = (u16*)(ws + 8388608);                       //   589,824 B
  u16* Wol2 = (u16*)(ws + 8388608 + 589824);              //    73,728 B (tot 9.05 MB)
  prep_fused  <<<dim3(1808), dim3(256), 0, stream>>>(x, w_dc, w_off, xh, Wl2, Wol2);
  deform_fused<<<dim3(1024), dim3(256), 0, stream>>>(xh, Wl2, Wol2, b_off, b_dc, out);
}

// Round 9
// 47.035 us; speedup vs baseline: 1.1748x; 1.1406x over previous
//
#include <hip/hip_runtime.h>
#include <hip/hip_fp16.h>

typedef unsigned short u16;
typedef unsigned int   u32;
typedef u32   u32x2  __attribute__((ext_vector_type(2)));
typedef u32   u32x4  __attribute__((ext_vector_type(4)));
typedef short short8 __attribute__((ext_vector_type(8)));
typedef float f32x4  __attribute__((ext_vector_type(4)));
typedef _Float16 half8 __attribute__((ext_vector_type(8)));

__device__ __forceinline__ u16 f2h(float f) { return __half_as_ushort(__float2half(f)); }
__device__ __forceinline__ f32x4 mfma16(short8 a, short8 b, f32x4 c) {
  return __builtin_amdgcn_mfma_f32_16x16x32_f16(
      __builtin_bit_cast(half8, a), __builtin_bit_cast(half8, b), c, 0, 0, 0);
}
__device__ __forceinline__ __half2 h2cast(u32 u) { return __builtin_bit_cast(__half2, u); }
__device__ __forceinline__ int refl(int v) { return v < 0 ? -v : (v > 63 ? 126 - v : v); }

// ---------------- fused prep: x NCHW f32 -> NHWC f16 ; weights -> MFMA order ----------------
__global__ __launch_bounds__(256) void prep_fused(const float* __restrict__ x,
                                                  const float* __restrict__ w_dc,
                                                  const float* __restrict__ w_off,
                                                  u16* __restrict__ xh,
                                                  u16* __restrict__ Wl2,
                                                  u16* __restrict__ Wol2) {
  int bid = blockIdx.x;
  int tid = threadIdx.x;
  if (bid < 512) {
    __shared__ float tile[128][65];
    int swz = (bid & 7) * 64 + (bid >> 3);
    int b = swz >> 6, h = swz & 63;
    for (int i = 0; i < 32; ++i) {
      int c = (tid >> 6) + i * 4;
      int w = tid & 63;
      tile[c][w] = x[(((size_t)b * 128 + c) * 64 + h) * 64 + w];
    }
    __syncthreads();
    u16* dst = xh + ((size_t)(b * 64 + h) * 64) * 128;
    for (int j = 0; j < 32; ++j) {
      int c = tid & 127;
      int w = (tid >> 7) + 2 * j;
      dst[w * 128 + c] = f2h(tile[c][w]);
    }
  } else {
    int idx = (bid - 512) * 256 + tid;        // 0..331775
    if (idx < 294912) {
      // Wl2 idx = (((kk*16+mtile)*4+ks)*64+lane)*8+e : o=mtile*16+(lane&15), c=ks*32+(lane>>4)*8+e
      int e = idx & 7, lane = (idx >> 3) & 63, ks = (idx >> 9) & 3;
      int mt = (idx >> 11) & 15, kk = idx >> 15;
      int o = mt * 16 + (lane & 15), c = ks * 32 + (lane >> 4) * 8 + e;
      Wl2[idx] = f2h(w_dc[(o * 128 + c) * 9 + kk]);
    } else {
      int i2 = idx - 294912;                  // 0..36863
      int e = i2 & 7, lane = (i2 >> 3) & 63, ks = (i2 >> 9) & 3;
      int mt = (i2 >> 11) & 1, kk = i2 >> 12;
      int co = mt * 16 + (lane & 15), c = ks * 32 + (lane >> 4) * 8 + e;
      Wol2[i2] = (co < 18) ? f2h(w_off[(co * 128 + c) * 9 + kk]) : (u16)0;
    }
  }
}

// ---------------- sampling-table entry (LDS) ----------------
__device__ __forceinline__ void make_entry_lds(u32x4* __restrict__ tbl, int kk,
                                               int ho, int wo, float offy, float offx) {
  int ki = kk / 3, kj = kk - ki * 3;
  float py = offy + (float)(ho + ki - 1);
  float px = offx + (float)(wo + kj - 1);
  float fy0 = floorf(py), fx0 = floorf(px);
  int y0 = (int)fy0, x0 = (int)fx0;
  float fy = py - fy0, fx = px - fx0;
  float w11 = fy * fx, w10 = fy - w11, w01 = fx - w11, w00 = 1.f - fy - fx + w11;
  bool iy0 = (y0 >= 0) & (y0 < 64), iy1 = (y0 >= -1) & (y0 < 63);
  bool ix0 = (x0 >= 0) & (x0 < 64), ix1 = (x0 >= -1) & (x0 < 63);
  int y0c = min(max(y0, 0), 63), x0c = min(max(x0, 0), 63);
  u32 addr00 = (u32)((y0c * 64 + x0c) * 128);          // u16-element offset
  u32 dx = (x0 >= 0 && x0 < 63) ? 128u : 0u;
  u32 dy = (y0 >= 0 && y0 < 63) ? 8192u : 0u;
  u32 wA = (u32)f2h((iy0 && ix0) ? w00 : 0.f) | ((u32)f2h((iy0 && ix1) ? w01 : 0.f) << 16);
  u32 wB = (u32)f2h((iy1 && ix0) ? w10 : 0.f) | ((u32)f2h((iy1 && ix1) ? w11 : 0.f) << 16);
  u32x4 ent; ent.x = addr00; ent.y = dx | (dy << 16); ent.z = wA; ent.w = wB;
  tbl[kk * 64 + wo] = ent;
}

// ---------------- fused: 64 l x 256 COUT per block, 8 waves, wave = 32co x 64l ----------------
__global__ __launch_bounds__(512, 4) void deform_fused(
    const u16* __restrict__ xh, const u16* __restrict__ Wl2,
    const u16* __restrict__ Wol2, const float* __restrict__ b_off,
    const float* __restrict__ b_dc, float* __restrict__ out) {
  union SMU {
    u16 slab[3][64][128];                                // 49152 B (phase A)
    struct { u16 cols[2][64][128]; u32x4 tbl[576]; } pb; // 32768 + 9216 (phase B)
  };
  __shared__ SMU sm;
  int bid = blockIdx.x;
  int b = bid & 7, ho = bid >> 3;          // batch -> XCD
  int tid = threadIdx.x, lane = tid & 63, wv = tid >> 6;   // wv 0..7
  int ln15 = lane & 15, kg = lane >> 4;
  const u16* xb = xh + (size_t)b * 524288;

  // ================= phase A: stage 3-row slab once =================
  {
    u32x4 st[6];
#pragma unroll
    for (int i = 0; i < 6; ++i) {
      int T = tid + i * 512;
      int r = T >> 10, w = (T >> 4) & 63, cb = (T & 15) * 8;
      int hr = refl(ho + r - 1);
      st[i] = *(const u32x4*)(xb + (hr * 64 + w) * 128 + cb);
    }
#pragma unroll
    for (int i = 0; i < 6; ++i) {
      int T = tid + i * 512;
      int r = T >> 10, w = (T >> 4) & 63, cb = (T & 15) * 8;
      *(u32x4*)&sm.slab[r][w][cb ^ ((w & 7) << 3)] = st[i];
    }
  }
  __syncthreads();

  // ---- offset conv: M=32(pad18) x N=64, 36 MFMA/wave burst, no barriers ----
  int mtA = wv & 1, ntA = wv >> 1;         // co-half, l-quarter
  int lq = ntA * 16 + ln15;                // 0..63
  f32x4 oacc = {0.f, 0.f, 0.f, 0.f};
  __builtin_amdgcn_s_setprio(1);
#pragma unroll
  for (int kk = 0; kk < 9; ++kk) {
    int ki = kk / 3, kj = kk - ki * 3;
    int j = refl(lq + kj - 1);
    const u16* wb = Wol2 + ((kk * 2 + mtA) * 4) * 512 + lane * 8;
    int sbj = (j & 7) << 3;
#pragma unroll
    for (int ks = 0; ks < 4; ++ks) {
      short8 af = *(const short8*)(wb + ks * 512);
      short8 bf = *(const short8*)&sm.slab[ki][j][(ks * 32 + kg * 8) ^ sbj];
      oacc = mfma16(af, bf, oacc);
    }
  }
  __builtin_amdgcn_s_setprio(0);
  __syncthreads();                         // slab reads done (pb aliases slab)

  // ---- write sampling table ----
  if (mtA == 0) {
    int kkA = 2 * kg, kkB = 2 * kg + 1;
    make_entry_lds(sm.pb.tbl, kkA, ho, lq, oacc[0] + b_off[2 * kkA], oacc[1] + b_off[2 * kkA + 1]);
    make_entry_lds(sm.pb.tbl, kkB, ho, lq, oacc[2] + b_off[2 * kkB], oacc[3] + b_off[2 * kkB + 1]);
  } else if (kg == 0) {
    make_entry_lds(sm.pb.tbl, 8, ho, lq, oacc[0] + b_off[16], oacc[1] + b_off[17]);
  }
  __syncthreads();                         // tbl visible

  // ================= phase B: deformable GEMM, 2-deep gather pipeline =================
  int tl0 = tid >> 4;                      // 0..31 ; tasks l = tl0, tl0+32
  int tcl = (tid & 15) * 8;
  int swzc = tcl ^ ((tl0 & 7) << 3);

  u32x4 gv[2][4];
  u32 gwAv[2], gwBv[2];
  auto gissue = [&](int g) {
#pragma unroll
    for (int i = 0; i < 2; ++i) {
      int l = tl0 + i * 32;
      u32x4 e = sm.pb.tbl[g * 64 + l];
      gwAv[i] = e.z; gwBv[i] = e.w;
      const u16* p = xb + e.x + tcl;
      u32 dxv = e.y & 0xffffu, dyv = e.y >> 16;
      gv[i][0] = *(const u32x4*)p;
      gv[i][1] = *(const u32x4*)(p + dxv);
      gv[i][2] = *(const u32x4*)(p + dyv);
      gv[i][3] = *(const u32x4*)(p + dyv + dxv);
    }
  };
  auto gwrite = [&](int dbuf) {
#pragma unroll
    for (int i = 0; i < 2; ++i) {
      int l = tl0 + i * 32;
      __half2 wA = h2cast(gwAv[i]), wB = h2cast(gwBv[i]);
      __half2 w00 = __half2half2(wA.x), w01 = __half2half2(wA.y);
      __half2 w10 = __half2half2(wB.x), w11 = __half2half2(wB.y);
      u32x4 pv;
#pragma unroll
      for (int wd = 0; wd < 4; ++wd) {
        __half2 r = __hmul2(h2cast(gv[i][0][wd]), w00);
        r = __hfma2(h2cast(gv[i][1][wd]), w01, r);
        r = __hfma2(h2cast(gv[i][2][wd]), w10, r);
        r = __hfma2(h2cast(gv[i][3][wd]), w11, r);
        pv[wd] = __builtin_bit_cast(u32, r);
      }
      *(u32x4*)&sm.pb.cols[dbuf][l][swzc] = pv;
    }
  };

  f32x4 acc[2][4];
#pragma unroll
  for (int m = 0; m < 2; ++m)
#pragma unroll
    for (int n = 0; n < 4; ++n) acc[m][n] = (f32x4){0.f, 0.f, 0.f, 0.f};

  // prologue: B(0) staged, gathers for B(1) in flight
  gissue(0); gwrite(0);
  gissue(1);
  __syncthreads();

  int swzb = (ln15 & 7) << 3;
  for (int kk = 0; kk < 9; ++kk) {
    int cur = kk & 1;
    // (1) A(kk): 8 x b128, issued first (FIFO slots 1-8)
    const u16* wbase = Wl2 + (size_t)kk * 32768 + lane * 8;
    short8 a[2][4];
#pragma unroll
    for (int mt = 0; mt < 2; ++mt)
#pragma unroll
      for (int ks = 0; ks < 4; ++ks)
        a[mt][ks] = *(const short8*)(wbase + (size_t)(((wv * 2 + mt) * 4) + ks) * 512);
    // (2) write B(kk+1) from gathers issued a full step ago (drain is cheap)
    if (kk < 8) gwrite(cur ^ 1);
    // (3) issue gathers for B(kk+2) (stay in flight through MFMA and the barrier region)
    if (kk < 7) gissue(kk + 2);
    // (4) MFMA burst: first a-use waits vmcnt(8) -> gathers remain outstanding
    __builtin_amdgcn_s_setprio(1);
#pragma unroll
    for (int ks = 0; ks < 4; ++ks) {
#pragma unroll
      for (int nt = 0; nt < 4; ++nt) {
        short8 bf = *(const short8*)&sm.pb.cols[cur][nt * 16 + ln15][(ks * 32 + kg * 8) ^ swzb];
#pragma unroll
        for (int mt = 0; mt < 2; ++mt)
          acc[mt][nt] = mfma16(a[mt][ks], bf, acc[mt][nt]);
      }
    }
    __builtin_amdgcn_s_setprio(0);
    __syncthreads();
  }

  // epilogue: wave wv owns COUT [wv*32, wv*32+32), all 64 l
#pragma unroll
  for (int mt = 0; mt < 2; ++mt) {
#pragma unroll
    for (int r = 0; r < 4; ++r) {
      int o = wv * 32 + mt * 16 + kg * 4 + r;
      float bias = b_dc[o];
      size_t base = ((size_t)(b * 256 + o)) * 4096 + ho * 64;
#pragma unroll
      for (int nt = 0; nt < 4; ++nt) {
        out[base + nt * 16 + ln15] = acc[mt][nt][r] + bias;
      }
    }
  }
}

extern "C" void kernel_launch(void* const* d_in, const int* in_sizes, int n_in,
                              void* d_out, int out_size, void* d_ws, size_t ws_size,
                              hipStream_t stream) {
  const float* x     = (const float*)d_in[0];
  const float* w_off = (const float*)d_in[1];
  const float* b_off = (const float*)d_in[2];
  const float* w_dc  = (const float*)d_in[3];
  const float* b_dc  = (const float*)d_in[4];
  float* out = (float*)d_out;
  char* ws = (char*)d_ws;
  u16* xh   = (u16*)ws;                                   // 8,388,608 B
  u16* Wl2  = (u16*)(ws + 8388608);                       //   589,824 B
  u16* Wol2 = (u16*)(ws + 8388608 + 589824);              //    73,728 B (tot 9.05 MB)
  prep_fused  <<<dim3(1808), dim3(256), 0, stream>>>(x, w_dc, w_off, xh, Wl2, Wol2);
  deform_fused<<<dim3(512),  dim3(512), 0, stream>>>(xh, Wl2, Wol2, b_off, b_dc, out);
}

// Round 10
// 45.740 us; speedup vs baseline: 1.2080x; 1.0283x over previous
//
#include <hip/hip_runtime.h>
#include <hip/hip_fp16.h>

typedef unsigned short u16;
typedef unsigned int   u32;
typedef u32   u32x2  __attribute__((ext_vector_type(2)));
typedef u32   u32x4  __attribute__((ext_vector_type(4)));
typedef short short8 __attribute__((ext_vector_type(8)));
typedef float f32x4  __attribute__((ext_vector_type(4)));
typedef _Float16 half8 __attribute__((ext_vector_type(8)));

__device__ __forceinline__ u16 f2h(float f) { return __half_as_ushort(__float2half(f)); }
__device__ __forceinline__ f32x4 mfma16(short8 a, short8 b, f32x4 c) {
  return __builtin_amdgcn_mfma_f32_16x16x32_f16(
      __builtin_bit_cast(half8, a), __builtin_bit_cast(half8, b), c, 0, 0, 0);
}
__device__ __forceinline__ __half2 h2cast(u32 u) { return __builtin_bit_cast(__half2, u); }
__device__ __forceinline__ int refl(int v) { return v < 0 ? -v : (v > 63 ? 126 - v : v); }

// ---------------- fused prep: x NCHW f32 -> NHWC f16 ; weights -> MFMA order ----------------
__global__ __launch_bounds__(256) void prep_fused(const float* __restrict__ x,
                                                  const float* __restrict__ w_dc,
                                                  const float* __restrict__ w_off,
                                                  u16* __restrict__ xh,
                                                  u16* __restrict__ Wl2,
                                                  u16* __restrict__ Wol2) {
  int bid = blockIdx.x;
  int tid = threadIdx.x;
  if (bid < 512) {
    __shared__ float tile[128][65];
    int swz = (bid & 7) * 64 + (bid >> 3);
    int b = swz >> 6, h = swz & 63;
    for (int i = 0; i < 32; ++i) {
      int c = (tid >> 6) + i * 4;
      int w = tid & 63;
      tile[c][w] = x[(((size_t)b * 128 + c) * 64 + h) * 64 + w];
    }
    __syncthreads();
    u16* dst = xh + ((size_t)(b * 64 + h) * 64) * 128;
    for (int j = 0; j < 32; ++j) {
      int c = tid & 127;
      int w = (tid >> 7) + 2 * j;
      dst[w * 128 + c] = f2h(tile[c][w]);
    }
  } else {
    int idx = (bid - 512) * 256 + tid;        // 0..331775
    if (idx < 294912) {
      // Wl2 idx = (((kk*16+mt)*4+ks)*64+lane)*8+e : o=mt*16+(lane&15), c=ks*32+(lane>>4)*8+e
      int e = idx & 7, lane = (idx >> 3) & 63, ks = (idx >> 9) & 3;
      int mt = (idx >> 11) & 15, kk = idx >> 15;
      int o = mt * 16 + (lane & 15), c = ks * 32 + (lane >> 4) * 8 + e;
      Wl2[idx] = f2h(w_dc[(o * 128 + c) * 9 + kk]);
    } else {
      int i2 = idx - 294912;                  // 0..36863
      int e = i2 & 7, lane = (i2 >> 3) & 63, ks = (i2 >> 9) & 3;
      int mt = (i2 >> 11) & 1, kk = i2 >> 12;
      int co = mt * 16 + (lane & 15), c = ks * 32 + (lane >> 4) * 8 + e;
      Wol2[i2] = (co < 18) ? f2h(w_off[(co * 128 + c) * 9 + kk]) : (u16)0;
    }
  }
}

// ---------------- sampling-table entry (LDS) ----------------
__device__ __forceinline__ void make_entry_lds(u32x4* __restrict__ tbl, int kk,
                                               int ho, int wo, float offy, float offx) {
  int ki = kk / 3, kj = kk - ki * 3;
  float py = offy + (float)(ho + ki - 1);
  float px = offx + (float)(wo + kj - 1);
  float fy0 = floorf(py), fx0 = floorf(px);
  int y0 = (int)fy0, x0 = (int)fx0;
  float fy = py - fy0, fx = px - fx0;
  float w11 = fy * fx, w10 = fy - w11, w01 = fx - w11, w00 = 1.f - fy - fx + w11;
  bool iy0 = (y0 >= 0) & (y0 < 64), iy1 = (y0 >= -1) & (y0 < 63);
  bool ix0 = (x0 >= 0) & (x0 < 64), ix1 = (x0 >= -1) & (x0 < 63);
  int y0c = min(max(y0, 0), 63), x0c = min(max(x0, 0), 63);
  u32 addr00 = (u32)((y0c * 64 + x0c) * 128);          // u16-element offset
  u32 dx = (x0 >= 0 && x0 < 63) ? 128u : 0u;
  u32 dy = (y0 >= 0 && y0 < 63) ? 8192u : 0u;
  u32 wA = (u32)f2h((iy0 && ix0) ? w00 : 0.f) | ((u32)f2h((iy0 && ix1) ? w01 : 0.f) << 16);
  u32 wB = (u32)f2h((iy1 && ix0) ? w10 : 0.f) | ((u32)f2h((iy1 && ix1) ? w11 : 0.f) << 16);
  u32x4 ent; ent.x = addr00; ent.y = dx | (dy << 16); ent.z = wA; ent.w = wB;
  tbl[kk * 64 + wo] = ent;
}

// ---------------- fused: producer/consumer split, 64l x 256co per block ----------------
__global__ __launch_bounds__(512, 4) void deform_fused(
    const u16* __restrict__ xh, const u16* __restrict__ Wl2,
    const u16* __restrict__ Wol2, const float* __restrict__ b_off,
    const float* __restrict__ b_dc, float* __restrict__ out) {
  union SMU {
    u16 slab[3][64][128];                                // 49152 B (phase A)
    struct { u16 cols[2][64][128]; u32x4 tbl[576]; } pb; // 32768 + 9216 (phase B)
  };
  __shared__ SMU sm;
  int bid = blockIdx.x;
  int b = bid & 7, ho = bid >> 3;          // batch -> XCD
  int tid = threadIdx.x, lane = tid & 63, wv = tid >> 6;   // wv 0..7
  int ln15 = lane & 15, kg = lane >> 4;
  const u16* xb = xh + (size_t)b * 524288;

  // ================= phase A: stage 3-row slab once =================
  {
    u32x4 st[6];
#pragma unroll
    for (int i = 0; i < 6; ++i) {
      int T = tid + i * 512;
      int r = T >> 10, w = (T >> 4) & 63, cb = (T & 15) * 8;
      int hr = refl(ho + r - 1);
      st[i] = *(const u32x4*)(xb + (hr * 64 + w) * 128 + cb);
    }
#pragma unroll
    for (int i = 0; i < 6; ++i) {
      int T = tid + i * 512;
      int r = T >> 10, w = (T >> 4) & 63, cb = (T & 15) * 8;
      *(u32x4*)&sm.slab[r][w][cb ^ ((w & 7) << 3)] = st[i];
    }
  }
  __syncthreads();

  // ---- offset conv: M=32(pad18) x N=64, 36 MFMA/wave burst ----
  int mtA = wv & 1, ntA = wv >> 1;
  int lq = ntA * 16 + ln15;                // 0..63
  f32x4 oacc = {0.f, 0.f, 0.f, 0.f};
  __builtin_amdgcn_s_setprio(1);
#pragma unroll
  for (int kk = 0; kk < 9; ++kk) {
    int ki = kk / 3, kj = kk - ki * 3;
    int j = refl(lq + kj - 1);
    const u16* wb = Wol2 + ((kk * 2 + mtA) * 4) * 512 + lane * 8;
    int sbj = (j & 7) << 3;
#pragma unroll
    for (int ks = 0; ks < 4; ++ks) {
      short8 af = *(const short8*)(wb + ks * 512);
      short8 bf = *(const short8*)&sm.slab[ki][j][(ks * 32 + kg * 8) ^ sbj];
      oacc = mfma16(af, bf, oacc);
    }
  }
  __builtin_amdgcn_s_setprio(0);
  __syncthreads();                         // slab reads done (pb aliases slab)

  if (mtA == 0) {
    int kkA = 2 * kg, kkB = 2 * kg + 1;
    make_entry_lds(sm.pb.tbl, kkA, ho, lq, oacc[0] + b_off[2 * kkA], oacc[1] + b_off[2 * kkA + 1]);
    make_entry_lds(sm.pb.tbl, kkB, ho, lq, oacc[2] + b_off[2 * kkB], oacc[3] + b_off[2 * kkB + 1]);
  } else if (kg == 0) {
    make_entry_lds(sm.pb.tbl, 8, ho, lq, oacc[0] + b_off[16], oacc[1] + b_off[17]);
  }
  __syncthreads();                         // tbl visible

  // ================= phase B: role split =================
  if (wv >= 4) {
    // ---------------- PRODUCER waves (4): gather + bilinear + ds_write ----------------
    int pt = tid & 255;                    // 0..255
    int tl = pt >> 4;                      // 0..15 ; tasks l = tl + i*16
    int tcl = (pt & 15) * 8;
    int swzc = tcl ^ ((tl & 7) << 3);      // (tl+16i)&7 == tl&7

    u32x4 gv[4][4];
    u32 gwA[4], gwB[4];
    auto gissue = [&](int g) {
#pragma unroll
      for (int i = 0; i < 4; ++i) {
        int l = tl + i * 16;
        u32x4 e = sm.pb.tbl[g * 64 + l];
        gwA[i] = e.z; gwB[i] = e.w;
        const u16* p = xb + e.x + tcl;
        u32 dxv = e.y & 0xffffu, dyv = e.y >> 16;
        gv[i][0] = *(const u32x4*)p;
        gv[i][1] = *(const u32x4*)(p + dxv);
        gv[i][2] = *(const u32x4*)(p + dyv);
        gv[i][3] = *(const u32x4*)(p + dyv + dxv);
      }
    };
    auto gwrite = [&](int dbuf) {
#pragma unroll
      for (int i = 0; i < 4; ++i) {
        int l = tl + i * 16;
        __half2 wA = h2cast(gwA[i]), wB = h2cast(gwB[i]);
        __half2 w00 = __half2half2(wA.x), w01 = __half2half2(wA.y);
        __half2 w10 = __half2half2(wB.x), w11 = __half2half2(wB.y);
        u32x4 pv;
#pragma unroll
        for (int wd = 0; wd < 4; ++wd) {
          __half2 r = __hmul2(h2cast(gv[i][0][wd]), w00);
          r = __hfma2(h2cast(gv[i][1][wd]), w01, r);
          r = __hfma2(h2cast(gv[i][2][wd]), w10, r);
          r = __hfma2(h2cast(gv[i][3][wd]), w11, r);
          pv[wd] = __builtin_bit_cast(u32, r);
        }
        *(u32x4*)&sm.pb.cols[dbuf][l][swzc] = pv;
      }
    };

    gissue(0); gwrite(0);
    gissue(1);
    __syncthreads();                       // B(0) ready
    for (int kk = 0; kk < 9; ++kk) {
      int cur = kk & 1;
      if (kk < 8) gwrite(cur ^ 1);         // gathers issued a full step ago
      if (kk < 7) gissue(kk + 2);
      __syncthreads();
    }
  } else {
    // ---------------- CONSUMER waves (4): A-load + ds_read B + MFMA ----------------
    f32x4 acc[4][4];
#pragma unroll
    for (int m = 0; m < 4; ++m)
#pragma unroll
      for (int n = 0; n < 4; ++n) acc[m][n] = (f32x4){0.f, 0.f, 0.f, 0.f};

    int swzb = (ln15 & 7) << 3;
    __syncthreads();                       // B(0) ready
    for (int kk = 0; kk < 9; ++kk) {
      int cur = kk & 1;
      const u16* wb = Wl2 + (size_t)kk * 32768 + lane * 8;
      short8 ac[4], an[4];
#pragma unroll
      for (int m = 0; m < 4; ++m)
        ac[m] = *(const short8*)(wb + (size_t)((wv * 4 + m) * 4) * 512);
#pragma unroll
      for (int ks = 0; ks < 4; ++ks) {
        if (ks < 3) {
#pragma unroll
          for (int m = 0; m < 4; ++m)
            an[m] = *(const short8*)(wb + (size_t)((wv * 4 + m) * 4 + ks + 1) * 512);
        }
        __builtin_amdgcn_s_setprio(1);
#pragma unroll
        for (int nt = 0; nt < 4; ++nt) {
          short8 bf = *(const short8*)&sm.pb.cols[cur][nt * 16 + ln15][(ks * 32 + kg * 8) ^ swzb];
#pragma unroll
          for (int m = 0; m < 4; ++m)
            acc[m][nt] = mfma16(ac[m], bf, acc[m][nt]);
        }
        __builtin_amdgcn_s_setprio(0);
        if (ks < 3) {
#pragma unroll
          for (int m = 0; m < 4; ++m) ac[m] = an[m];
        }
      }
      __syncthreads();
    }

    // epilogue: wave wv owns COUT [wv*64, wv*64+64), all 64 l
#pragma unroll
    for (int m = 0; m < 4; ++m) {
#pragma unroll
      for (int r = 0; r < 4; ++r) {
        int o = wv * 64 + m * 16 + kg * 4 + r;
        float bias = b_dc[o];
        size_t base = ((size_t)(b * 256 + o)) * 4096 + ho * 64;
#pragma unroll
        for (int nt = 0; nt < 4; ++nt) {
          out[base + nt * 16 + ln15] = acc[m][nt][r] + bias;
        }
      }
    }
  }
}

extern "C" void kernel_launch(void* const* d_in, const int* in_sizes, int n_in,
                              void* d_out, int out_size, void* d_ws, size_t ws_size,
                              hipStream_t stream) {
  const float* x     = (const float*)d_in[0];
  const float* w_off = (const float*)d_in[1];
  const float* b_off = (const float*)d_in[2];
  const float* w_dc  = (const float*)d_in[3];
  const float* b_dc  = (const float*)d_in[4];
  float* out = (float*)d_out;
  char* ws = (char*)d_ws;
  u16* xh   = (u16*)ws;                                   // 8,388,608 B
  u16* Wl2  = (u16*)(ws + 8388608);                       //   589,824 B
  u16* Wol2 = (u16*)(ws + 8388608 + 589824);              //    73,728 B (tot 9.05 MB)
  prep_fused  <<<dim3(1808), dim3(256), 0, stream>>>(x, w_dc, w_off, xh, Wl2, Wol2);
  deform_fused<<<dim3(512),  dim3(512), 0, stream>>>(xh, Wl2, Wol2, b_off, b_dc, out);
}

// Round 11
// 45.579 us; speedup vs baseline: 1.2123x; 1.0035x over previous
//
#include <hip/hip_runtime.h>
#include <hip/hip_fp16.h>

typedef unsigned short u16;
typedef unsigned int   u32;
typedef u32   u32x2  __attribute__((ext_vector_type(2)));
typedef u32   u32x4  __attribute__((ext_vector_type(4)));
typedef short short8 __attribute__((ext_vector_type(8)));
typedef float f32x4  __attribute__((ext_vector_type(4)));
typedef _Float16 half8 __attribute__((ext_vector_type(8)));

__device__ __forceinline__ u16 f2h(float f) { return __half_as_ushort(__float2half(f)); }
__device__ __forceinline__ f32x4 mfma16(short8 a, short8 b, f32x4 c) {
  return __builtin_amdgcn_mfma_f32_16x16x32_f16(
      __builtin_bit_cast(half8, a), __builtin_bit_cast(half8, b), c, 0, 0, 0);
}
__device__ __forceinline__ __half2 h2cast(u32 u) { return __builtin_bit_cast(__half2, u); }
__device__ __forceinline__ int refl(int v) { return v < 0 ? -v : (v > 63 ? 126 - v : v); }

// Barrier that does NOT drain vmcnt: LDS ops (the only cross-wave hazard with
// double-buffered cols) are drained via lgkmcnt(0); global loads issued for
// kk+2 stay in flight across the barrier (T4 counted-vmcnt pattern).
__device__ __forceinline__ void softbar() {
  asm volatile("s_waitcnt lgkmcnt(0)" ::: "memory");
  __builtin_amdgcn_s_barrier();
  asm volatile("" ::: "memory");
}

// ---------------- fused prep: x NCHW f32 -> NHWC f16 ; weights -> MFMA order ----------------
__global__ __launch_bounds__(256) void prep_fused(const float* __restrict__ x,
                                                  const float* __restrict__ w_dc,
                                                  const float* __restrict__ w_off,
                                                  u16* __restrict__ xh,
                                                  u16* __restrict__ Wl2,
                                                  u16* __restrict__ Wol2) {
  int bid = blockIdx.x;
  int tid = threadIdx.x;
  if (bid < 512) {
    __shared__ float tile[128][65];
    int swz = (bid & 7) * 64 + (bid >> 3);
    int b = swz >> 6, h = swz & 63;
    for (int i = 0; i < 32; ++i) {
      int c = (tid >> 6) + i * 4;
      int w = tid & 63;
      tile[c][w] = x[(((size_t)b * 128 + c) * 64 + h) * 64 + w];
    }
    __syncthreads();
    u16* dst = xh + ((size_t)(b * 64 + h) * 64) * 128;
    for (int j = 0; j < 32; ++j) {
      int c = tid & 127;
      int w = (tid >> 7) + 2 * j;
      dst[w * 128 + c] = f2h(tile[c][w]);
    }
  } else {
    int idx = (bid - 512) * 256 + tid;        // 0..331775
    if (idx < 294912) {
      // Wl2 idx = (((kk*16+mt)*4+ks)*64+lane)*8+e : o=mt*16+(lane&15), c=ks*32+(lane>>4)*8+e
      int e = idx & 7, lane = (idx >> 3) & 63, ks = (idx >> 9) & 3;
      int mt = (idx >> 11) & 15, kk = idx >> 15;
      int o = mt * 16 + (lane & 15), c = ks * 32 + (lane >> 4) * 8 + e;
      Wl2[idx] = f2h(w_dc[(o * 128 + c) * 9 + kk]);
    } else {
      int i2 = idx - 294912;                  // 0..36863
      int e = i2 & 7, lane = (i2 >> 3) & 63, ks = (i2 >> 9) & 3;
      int mt = (i2 >> 11) & 1, kk = i2 >> 12;
      int co = mt * 16 + (lane & 15), c = ks * 32 + (lane >> 4) * 8 + e;
      Wol2[i2] = (co < 18) ? f2h(w_off[(co * 128 + c) * 9 + kk]) : (u16)0;
    }
  }
}

// ---------------- sampling-table entry (LDS) ----------------
__device__ __forceinline__ void make_entry_lds(u32x4* __restrict__ tbl, int kk,
                                               int ho, int wo, float offy, float offx) {
  int ki = kk / 3, kj = kk - ki * 3;
  float py = offy + (float)(ho + ki - 1);
  float px = offx + (float)(wo + kj - 1);
  float fy0 = floorf(py), fx0 = floorf(px);
  int y0 = (int)fy0, x0 = (int)fx0;
  float fy = py - fy0, fx = px - fx0;
  float w11 = fy * fx, w10 = fy - w11, w01 = fx - w11, w00 = 1.f - fy - fx + w11;
  bool iy0 = (y0 >= 0) & (y0 < 64), iy1 = (y0 >= -1) & (y0 < 63);
  bool ix0 = (x0 >= 0) & (x0 < 64), ix1 = (x0 >= -1) & (x0 < 63);
  int y0c = min(max(y0, 0), 63), x0c = min(max(x0, 0), 63);
  u32 addr00 = (u32)((y0c * 64 + x0c) * 128);          // u16-element offset
  u32 dx = (x0 >= 0 && x0 < 63) ? 128u : 0u;
  u32 dy = (y0 >= 0 && y0 < 63) ? 8192u : 0u;
  u32 wA = (u32)f2h((iy0 && ix0) ? w00 : 0.f) | ((u32)f2h((iy0 && ix1) ? w01 : 0.f) << 16);
  u32 wB = (u32)f2h((iy1 && ix0) ? w10 : 0.f) | ((u32)f2h((iy1 && ix1) ? w11 : 0.f) << 16);
  u32x4 ent; ent.x = addr00; ent.y = dx | (dy << 16); ent.z = wA; ent.w = wB;
  tbl[kk * 64 + wo] = ent;
}

// ---------------- fused: producer/consumer split, 64l x 256co per block ----------------
__global__ __launch_bounds__(512, 4) void deform_fused(
    const u16* __restrict__ xh, const u16* __restrict__ Wl2,
    const u16* __restrict__ Wol2, const float* __restrict__ b_off,
    const float* __restrict__ b_dc, float* __restrict__ out) {
  union SMU {
    u16 slab[3][64][128];                                // 49152 B (phase A)
    struct { u16 cols[2][64][128]; u32x4 tbl[576]; } pb; // 32768 + 9216 (phase B)
  };
  __shared__ SMU sm;
  int bid = blockIdx.x;
  int b = bid & 7, ho = bid >> 3;          // batch -> XCD
  int tid = threadIdx.x, lane = tid & 63, wv = tid >> 6;   // wv 0..7
  int ln15 = lane & 15, kg = lane >> 4;
  const u16* xb = xh + (size_t)b * 524288;

  // ================= phase A: stage 3-row slab once =================
  {
    u32x4 st[6];
#pragma unroll
    for (int i = 0; i < 6; ++i) {
      int T = tid + i * 512;
      int r = T >> 10, w = (T >> 4) & 63, cb = (T & 15) * 8;
      int hr = refl(ho + r - 1);
      st[i] = *(const u32x4*)(xb + (hr * 64 + w) * 128 + cb);
    }
#pragma unroll
    for (int i = 0; i < 6; ++i) {
      int T = tid + i * 512;
      int r = T >> 10, w = (T >> 4) & 63, cb = (T & 15) * 8;
      *(u32x4*)&sm.slab[r][w][cb ^ ((w & 7) << 3)] = st[i];
    }
  }
  __syncthreads();

  // ---- offset conv: M=32(pad18) x N=64, 36 MFMA/wave burst ----
  int mtA = wv & 1, ntA = wv >> 1;
  int lq = ntA * 16 + ln15;                // 0..63
  f32x4 oacc = {0.f, 0.f, 0.f, 0.f};
  __builtin_amdgcn_s_setprio(1);
#pragma unroll
  for (int kk = 0; kk < 9; ++kk) {
    int ki = kk / 3, kj = kk - ki * 3;
    int j = refl(lq + kj - 1);
    const u16* wb = Wol2 + ((kk * 2 + mtA) * 4) * 512 + lane * 8;
    int sbj = (j & 7) << 3;
#pragma unroll
    for (int ks = 0; ks < 4; ++ks) {
      short8 af = *(const short8*)(wb + ks * 512);
      short8 bf = *(const short8*)&sm.slab[ki][j][(ks * 32 + kg * 8) ^ sbj];
      oacc = mfma16(af, bf, oacc);
    }
  }
  __builtin_amdgcn_s_setprio(0);
  __syncthreads();                         // slab reads done (pb aliases slab)

  if (mtA == 0) {
    int kkA = 2 * kg, kkB = 2 * kg + 1;
    make_entry_lds(sm.pb.tbl, kkA, ho, lq, oacc[0] + b_off[2 * kkA], oacc[1] + b_off[2 * kkA + 1]);
    make_entry_lds(sm.pb.tbl, kkB, ho, lq, oacc[2] + b_off[2 * kkB], oacc[3] + b_off[2 * kkB + 1]);
  } else if (kg == 0) {
    make_entry_lds(sm.pb.tbl, 8, ho, lq, oacc[0] + b_off[16], oacc[1] + b_off[17]);
  }
  __syncthreads();                         // tbl visible

  // ================= phase B: role split, counted-vmcnt barriers =================
  if (wv >= 4) {
    // ---------------- PRODUCER waves (4): gather + bilinear + ds_write ----------------
    int pt = tid & 255;                    // 0..255
    int tl = pt >> 4;                      // 0..15 ; tasks l = tl + i*16
    int tcl = (pt & 15) * 8;
    int swzc = tcl ^ ((tl & 7) << 3);      // (tl+16i)&7 == tl&7

    u32x4 gv[4][4];
    u32 gwA[4], gwB[4];
    auto gissue = [&](int g) {
#pragma unroll
      for (int i = 0; i < 4; ++i) {
        int l = tl + i * 16;
        u32x4 e = sm.pb.tbl[g * 64 + l];
        gwA[i] = e.z; gwB[i] = e.w;
        const u16* p = xb + e.x + tcl;
        u32 dxv = e.y & 0xffffu, dyv = e.y >> 16;
        gv[i][0] = *(const u32x4*)p;
        gv[i][1] = *(const u32x4*)(p + dxv);
        gv[i][2] = *(const u32x4*)(p + dyv);
        gv[i][3] = *(const u32x4*)(p + dyv + dxv);
      }
    };
    auto gwrite = [&](int dbuf) {
#pragma unroll
      for (int i = 0; i < 4; ++i) {
        int l = tl + i * 16;
        __half2 wA = h2cast(gwA[i]), wB = h2cast(gwB[i]);
        __half2 w00 = __half2half2(wA.x), w01 = __half2half2(wA.y);
        __half2 w10 = __half2half2(wB.x), w11 = __half2half2(wB.y);
        u32x4 pv;
#pragma unroll
        for (int wd = 0; wd < 4; ++wd) {
          __half2 r = __hmul2(h2cast(gv[i][0][wd]), w00);
          r = __hfma2(h2cast(gv[i][1][wd]), w01, r);
          r = __hfma2(h2cast(gv[i][2][wd]), w10, r);
          r = __hfma2(h2cast(gv[i][3][wd]), w11, r);
          pv[wd] = __builtin_bit_cast(u32, r);
        }
        *(u32x4*)&sm.pb.cols[dbuf][l][swzc] = pv;
      }
    };

    gissue(0); gwrite(0);
    gissue(1);
    softbar();                             // B(0) ready; B(1) gathers stay in flight
    for (int kk = 0; kk < 9; ++kk) {
      int cur = kk & 1;
      if (kk < 8) gwrite(cur ^ 1);         // counted vmcnt wait on gv(kk+1) only
      if (kk < 7) gissue(kk + 2);          // these survive the barrier below
      softbar();
    }
  } else {
    // ---------------- CONSUMER waves (4): A-load + ds_read B + MFMA ----------------
    f32x4 acc[4][4];
#pragma unroll
    for (int m = 0; m < 4; ++m)
#pragma unroll
      for (int n = 0; n < 4; ++n) acc[m][n] = (f32x4){0.f, 0.f, 0.f, 0.f};

    int swzb = (ln15 & 7) << 3;
    softbar();                             // B(0) ready
    for (int kk = 0; kk < 9; ++kk) {
      int cur = kk & 1;
      const u16* wb = Wl2 + (size_t)kk * 32768 + lane * 8;
      short8 ac[4], an[4];
#pragma unroll
      for (int m = 0; m < 4; ++m)
        ac[m] = *(const short8*)(wb + (size_t)((wv * 4 + m) * 4) * 512);
#pragma unroll
      for (int ks = 0; ks < 4; ++ks) {
        if (ks < 3) {
#pragma unroll
          for (int m = 0; m < 4; ++m)
            an[m] = *(const short8*)(wb + (size_t)((wv * 4 + m) * 4 + ks + 1) * 512);
        }
        __builtin_amdgcn_s_setprio(1);
#pragma unroll
        for (int nt = 0; nt < 4; ++nt) {
          short8 bf = *(const short8*)&sm.pb.cols[cur][nt * 16 + ln15][(ks * 32 + kg * 8) ^ swzb];
#pragma unroll
          for (int m = 0; m < 4; ++m)
            acc[m][nt] = mfma16(ac[m], bf, acc[m][nt]);
        }
        __builtin_amdgcn_s_setprio(0);
        if (ks < 3) {
#pragma unroll
          for (int m = 0; m < 4; ++m) ac[m] = an[m];
        }
      }
      softbar();
    }

    // epilogue: wave wv owns COUT [wv*64, wv*64+64), all 64 l
#pragma unroll
    for (int m = 0; m < 4; ++m) {
#pragma unroll
      for (int r = 0; r < 4; ++r) {
        int o = wv * 64 + m * 16 + kg * 4 + r;
        float bias = b_dc[o];
        size_t base = ((size_t)(b * 256 + o)) * 4096 + ho * 64;
#pragma unroll
        for (int nt = 0; nt < 4; ++nt) {
          out[base + nt * 16 + ln15] = acc[m][nt][r] + bias;
        }
      }
    }
  }
}

extern "C" void kernel_launch(void* const* d_in, const int* in_sizes, int n_in,
                              void* d_out, int out_size, void* d_ws, size_t ws_size,
                              hipStream_t stream) {
  const float* x     = (const float*)d_in[0];
  const float* w_off = (const float*)d_in[1];
  const float* b_off = (const float*)d_in[2];
  const float* w_dc  = (const float*)d_in[3];
  const float* b_dc  = (const float*)d_in[4];
  float* out = (float*)d_out;
  char* ws = (char*)d_ws;
  u16* xh   = (u16*)ws;                                   // 8,388,608 B
  u16* Wl2  = (u16*)(ws + 8388608);                       //   589,824 B
  u16* Wol2 = (u16*)(ws + 8388608 + 589824);              //    73,728 B (tot 9.05 MB)
  prep_fused  <<<dim3(1808), dim3(256), 0, stream>>>(x, w_dc, w_off, xh, Wl2, Wol2);
  deform_fused<<<dim3(512),  dim3(512), 0, stream>>>(xh, Wl2, Wol2, b_off, b_dc, out);
}